// Round 4
// baseline (1122.590 us; speedup 1.0000x reference)
//
#include <hip/hip_runtime.h>
#include <math.h>

#define T_LEN 3000
#define HID 64

typedef _Float16 f16;
typedef f16 f16x2 __attribute__((ext_vector_type(2)));
typedef f16 f16x8 __attribute__((ext_vector_type(8)));
typedef float f32x4 __attribute__((ext_vector_type(4)));

__device__ __forceinline__ float sigmoid_f(float v) {
    return __builtin_amdgcn_rcpf(1.0f + __expf(-v));
}
__device__ __forceinline__ float tanh_f(float v) {
    return fmaf(2.0f, __builtin_amdgcn_rcpf(1.0f + __expf(-2.0f * v)), -1.0f);
}
// Hardened: bit_cast the builtin's half2 so __fp16/_Float16 vector-type
// mismatch can never be a compile error.
__device__ __forceinline__ f16x2 pkrtz(float a, float b) {
    return __builtin_bit_cast(f16x2, __builtin_amdgcn_cvt_pkrtz(a, b));
}

// One wave per batch element, zero s_barriers.
// R10 = R9 resubmit (R9 bench died in infra: "container failed twice", no
// kernel verdict) + two hardenings (bit_cast on cvt_pkrtz; persistent zero
// A_h scratch, only elem0 rewritten per step).
//
// Core idea: the ~150-200cy/step LDS round-trip for h (ds_write f16 ->
// barrier -> 2x ds_read_b128 @ ~120cy latency, nothing to hide it behind at
// 1 wave) is replaced by an in-pipe broadcast: 4 tiny MFMAs with constant
// 0/1 selector B-fragments redistribute h (one value per lane) into
// A-fragment layout.
//   A_h: lane l holds (f16)h at elem0 -> A_h[col][8*grp] = h[16*grp+col]
//   Bsel_u: 1.0 at elem0 of lanes grp==u (all cols) -> D_u[r][c] = h[16u+r]
//   => lane l, tile u, reg j receives h[16u + 4*grp + j]   (m89 D layout)
// Repack via cvt_pkrtz is EXACT (values are f16-representable), so numerics
// match the LDS version bit-for-bit; the single h->f16 cvt stays RNE.
// The induced k-permutation (A0 slot k=8g+j holds h[16*(j>>2)+4g+(j&3)]) is
// baked into the weight preload (A and B share the elem->k map).
// R8 lessons: weights/selectors deliberately AGPR-resident (MFMA reads AGPR
// operands free; only VALU-touched data needs arch VGPRs) -> no asm pins;
// chained K-halves (R8's split cost +40cy/step of VALU).
__global__
__attribute__((amdgpu_flat_work_group_size(64, 64), amdgpu_waves_per_eu(1, 1)))
void gru_bcast(
    const float* __restrict__ x,     // (B, T, 1)
    const float* __restrict__ W_ih,  // (192, 1)
    const float* __restrict__ W_hh,  // (192, 64)
    const float* __restrict__ b_ih,  // (192,)
    const float* __restrict__ b_hh,  // (192,)
    const float* __restrict__ W_fc,  // (1, 64)
    const float* __restrict__ b_fc,  // (1,)
    float* __restrict__ out)         // (B,)
{
    const int b   = blockIdx.x;
    const int l   = threadIdx.x;   // 0..63; lane l owns hidden unit l
    const int col = l & 15;        // unit-within-tile / D column
    const int grp = l >> 4;        // k-group
    const long xbase = (long)b * T_LEN;

    __shared__ float x_lds[64];

    // ---- one-time: W_hh -> B fragments (f16) under the broadcast sigma ----
    // elem j of (tile t, half H) = W_hh[16t+col][32H + 16*(j>>2) + 4*grp + (j&3)]
    f16x8 Bf[12][2];
#pragma unroll
    for (int t = 0; t < 12; ++t) {
#pragma unroll
        for (int hf = 0; hf < 2; ++hf) {
            const float* p = W_hh + (size_t)(16 * t + col) * HID + 32 * hf + 4 * grp;
            const float4 a = *reinterpret_cast<const float4*>(p);        // j=0..3
            const float4 c = *reinterpret_cast<const float4*>(p + 16);   // j=4..7
            f16x8 v;
            v[0] = (f16)a.x; v[1] = (f16)a.y; v[2] = (f16)a.z; v[3] = (f16)a.w;
            v[4] = (f16)c.x; v[5] = (f16)c.y; v[6] = (f16)c.z; v[7] = (f16)c.w;
            Bf[t][hf] = v;
        }
    }

    // ---- broadcast selector fragments: Bsel_u has 1.0 at elem0, lanes grp==u ----
    f16x8 bsel[4];
#pragma unroll
    for (int u = 0; u < 4; ++u) {
        f16x8 s;
#pragma unroll
        for (int j = 0; j < 8; ++j) s[j] = (f16)0.0f;
        if (grp == u) s[0] = (f16)1.0f;
        bsel[u] = s;
    }

    const float wihr = W_ih[l],        wihz = W_ih[64 + l],   wihn = W_ih[128 + l];
    const float br   = b_ih[l]        + b_hh[l];
    const float bz   = b_ih[64 + l]   + b_hh[64 + l];
    const float bin  = b_ih[128 + l];
    const float bhn  = b_hh[128 + l];

    // init x pipeline (single wave: DS in-order; barrier only at refills)
    x_lds[l] = x[xbase + l];
    float xnxt = (64 + l < T_LEN) ? x[xbase + 64 + l] : 0.0f;
    __builtin_amdgcn_wave_barrier();

    float h = 0.0f;  // lane l holds h[l] in fp32
    union AU { f16x8 v8; f16x2 v2[4]; };
    AU a0, a1, ah;
#pragma unroll
    for (int j = 0; j < 8; ++j) {
        a0.v8[j] = (f16)0.0f; a1.v8[j] = (f16)0.0f; ah.v8[j] = (f16)0.0f;
    }

    const f32x4 zf = {0.f, 0.f, 0.f, 0.f};
    const bool s0 = (grp & 1) != 0;
    const bool s1 = (grp & 2) != 0;

    float xcur = x_lds[0];  // prefetched x_t (uniform broadcast read)

    for (int t = 0; t < T_LEN; ++t) {
        const int j = t & 63;
        // x-gate contributions (xcur prefetched last iteration -> off-path)
        const float gxr = fmaf(xcur, wihr, br);
        const float gxz = fmaf(xcur, wihz, bz);
        const float gxn = fmaf(xcur, wihn, bin);

        // ---- matvec: 24 MFMA, chained K-halves, gate order r -> n -> z ----
        float sr[4], sn[4], sz[4];
#pragma unroll
        for (int q = 0; q < 4; ++q) {
            f32x4 c0 = __builtin_amdgcn_mfma_f32_16x16x32_f16(a0.v8, Bf[q][0], zf, 0, 0, 0);
            f32x4 cc = __builtin_amdgcn_mfma_f32_16x16x32_f16(a1.v8, Bf[q][1], c0, 0, 0, 0);
            sr[q] = cc[0];
        }
#pragma unroll
        for (int q = 0; q < 4; ++q) {
            f32x4 c0 = __builtin_amdgcn_mfma_f32_16x16x32_f16(a0.v8, Bf[8 + q][0], zf, 0, 0, 0);
            f32x4 cc = __builtin_amdgcn_mfma_f32_16x16x32_f16(a1.v8, Bf[8 + q][1], c0, 0, 0, 0);
            sn[q] = cc[0];
        }
#pragma unroll
        for (int q = 0; q < 4; ++q) {
            f32x4 c0 = __builtin_amdgcn_mfma_f32_16x16x32_f16(a0.v8, Bf[4 + q][0], zf, 0, 0, 0);
            f32x4 cc = __builtin_amdgcn_mfma_f32_16x16x32_f16(a1.v8, Bf[4 + q][1], c0, 0, 0, 0);
            sz[q] = cc[0];
        }

        const float ar  = s1 ? (s0 ? sr[3] : sr[2]) : (s0 ? sr[1] : sr[0]);
        const float r   = sigmoid_f(gxr + ar);
        const float an  = s1 ? (s0 ? sn[3] : sn[2]) : (s0 ? sn[1] : sn[0]);
        const float az  = s1 ? (s0 ? sz[3] : sz[2]) : (s0 ? sz[1] : sz[0]);
        const float z   = sigmoid_f(gxz + az);
        const float n   = tanh_f(fmaf(r, an + bhn, gxn));

        h = fmaf(z, h - n, n);  // (1-z)*n + z*h

        // ---- broadcast h -> next-step A fragments (4 MFMAs, no LDS) ----
        ah.v2[0].x = (f16)h;   // rest of ah stays zero (set before the loop)
        f32x4 d0 = __builtin_amdgcn_mfma_f32_16x16x32_f16(ah.v8, bsel[0], zf, 0, 0, 0);
        f32x4 d1 = __builtin_amdgcn_mfma_f32_16x16x32_f16(ah.v8, bsel[1], zf, 0, 0, 0);
        f32x4 d2 = __builtin_amdgcn_mfma_f32_16x16x32_f16(ah.v8, bsel[2], zf, 0, 0, 0);
        f32x4 d3 = __builtin_amdgcn_mfma_f32_16x16x32_f16(ah.v8, bsel[3], zf, 0, 0, 0);
        // repack (exact: values are f16-representable)
        a0.v2[0] = pkrtz(d0[0], d0[1]);
        a0.v2[1] = pkrtz(d0[2], d0[3]);
        a0.v2[2] = pkrtz(d1[0], d1[1]);
        a0.v2[3] = pkrtz(d1[2], d1[3]);
        a1.v2[0] = pkrtz(d2[0], d2[1]);
        a1.v2[1] = pkrtz(d2[2], d2[3]);
        a1.v2[2] = pkrtz(d3[0], d3[1]);
        a1.v2[3] = pkrtz(d3[2], d3[3]);

        // ---- x pipeline ----
        if (j == 63) {
            __builtin_amdgcn_wave_barrier();
            x_lds[l] = xnxt;
            const int idx = t + 65 + l;  // chunk after next
            xnxt = (idx < T_LEN) ? x[xbase + idx] : 0.0f;
            __builtin_amdgcn_wave_barrier();
        }
        xcur = x_lds[(t + 1) & 63];  // prefetch next step's x (off-path)
    }

    // ---- epilogue: out[b] = h . W_fc + b_fc (fp32) ----
    float v = h * W_fc[l];
#pragma unroll
    for (int off = 32; off > 0; off >>= 1) v += __shfl_down(v, off);
    if (l == 0) out[b] = v + b_fc[0];
}

extern "C" void kernel_launch(void* const* d_in, const int* in_sizes, int n_in,
                              void* d_out, int out_size, void* d_ws, size_t ws_size,
                              hipStream_t stream) {
    const float* x    = (const float*)d_in[0];
    const float* W_ih = (const float*)d_in[1];
    const float* W_hh = (const float*)d_in[2];
    const float* b_ih = (const float*)d_in[3];
    const float* b_hh = (const float*)d_in[4];
    const float* W_fc = (const float*)d_in[5];
    const float* b_fc = (const float*)d_in[6];
    float* out = (float*)d_out;

    const int B = 256;  // in_sizes[0] = B*T = 768000 -> B=256, T=3000
    gru_bcast<<<B, 64, 0, stream>>>(x, W_ih, W_hh, b_ih, b_hh, W_fc, b_fc, out);
}

// Round 5
// 645.477 us; speedup vs baseline: 1.7392x; 1.7392x over previous
//
#include <hip/hip_runtime.h>
#include <math.h>

#define T_LEN 3000
#define HID 64

typedef _Float16 f16;
typedef f16 f16x8 __attribute__((ext_vector_type(8)));
typedef float f32x4 __attribute__((ext_vector_type(4)));

__device__ __forceinline__ float sigmoid_f(float v) {
    return __builtin_amdgcn_rcpf(1.0f + __expf(-v));
}
__device__ __forceinline__ float tanh_f(float v) {
    return fmaf(2.0f, __builtin_amdgcn_rcpf(1.0f + __expf(-2.0f * v)), -1.0f);
}

// R11: 4-wave split of the matvec.
// Calibrated model from R7/R8/R10 deltas: one 16x16x32 MFMA BLOCKS its wave
// ~16cy (MfmaUtil 12.9%*4SIMD*746cy = 385cy = 24*16; R10's +4 MFMA/+8 pkrtz
// cost exactly the predicted +120cy). R7 was issue-bound: 385cy MFMA-block +
// ~316cy VALU on ONE wave. Fix: spread the 12 tiles x 2 K-halves over 4
// waves on 4 SIMDs (4 independent MFMA pipes): 6 MFMAs/wave = 96cy block.
// Wave w owns row-tile w of all 3 gates -> lane l owns unit u=16w+(l&15):
//  - acc extraction is acc[0] directly, NO cndmask select tree (R7 paid ~40cy)
//  - gates computed once per unit (4x lane redundancy across grp, free)
// h exchange: double-buffered 128B LDS f16 buffer, ONE __syncthreads per
// step (write hbuf[nxt], barrier, read hbuf[cur] next step -> no race).
// x: per-lane register window + uniform v_readlane broadcast (no LDS, no
// extra sync); refill global load issued 64 steps ahead (latency amortized).
// Fragment math identical to R7 (harness-verified): A0=h[8g..8g+7],
// A1=h[32+8g..], Bf elem j = W_hh[rowbase+col][8g+32hf+j], D read at reg 0.
__global__ __launch_bounds__(256, 1)
void gru_4wave(
    const float* __restrict__ x,     // (B, T, 1)
    const float* __restrict__ W_ih,  // (192, 1)
    const float* __restrict__ W_hh,  // (192, 64)
    const float* __restrict__ b_ih,  // (192,)
    const float* __restrict__ b_hh,  // (192,)
    const float* __restrict__ W_fc,  // (1, 64)
    const float* __restrict__ b_fc,  // (1,)
    float* __restrict__ out)         // (B,)
{
    const int tid = threadIdx.x;
    const int w   = tid >> 6;      // wave 0..3 -> owns units 16w..16w+15
    const int l   = tid & 63;
    const int col = l & 15;
    const int grp = l >> 4;        // k-group for A/B fragments (redundant dim)
    const int b   = blockIdx.x;
    const int u   = 16 * w + col;  // this lane's hidden unit
    const long xbase = (long)b * T_LEN;

    __shared__ __align__(16) f16 hbuf[2][HID];  // double-buffered h (f16)
    __shared__ float hf32[HID];                 // epilogue (f32 exact)

    // ---- one-time: this wave's W_hh tiles -> B fragments (f16) ----
    // gate g row base = 64*g + 16*w; B slot (lane, elem j) =
    // W_hh[base + col][8*grp + 32*hf + j]  (identical mapping to R7)
    f16x8 Bf[3][2];
#pragma unroll
    for (int g = 0; g < 3; ++g) {
#pragma unroll
        for (int hf = 0; hf < 2; ++hf) {
            const float* p = W_hh + (size_t)(64 * g + 16 * w + col) * HID
                           + 8 * grp + 32 * hf;
            const float4 a = *reinterpret_cast<const float4*>(p);
            const float4 c = *reinterpret_cast<const float4*>(p + 4);
            f16x8 v;
            v[0] = (f16)a.x; v[1] = (f16)a.y; v[2] = (f16)a.z; v[3] = (f16)a.w;
            v[4] = (f16)c.x; v[5] = (f16)c.y; v[6] = (f16)c.z; v[7] = (f16)c.w;
            Bf[g][hf] = v;
        }
    }

    // per-unit scalars (lane-redundant across grp, consistent)
    const float wihr = W_ih[u],        wihz = W_ih[64 + u],   wihn = W_ih[128 + u];
    const float br   = b_ih[u]        + b_hh[u];
    const float bz   = b_ih[64 + u]   + b_hh[64 + u];
    const float bin  = b_ih[128 + u];
    const float bhn  = b_hh[128 + u];

    // x window in registers: lane j holds x[t0 + j]; broadcast via readlane
    float xwin = x[xbase + l];
    float xnxt = (64 + l < T_LEN) ? x[xbase + 64 + l] : 0.0f;

    if (tid < HID) hbuf[0][tid] = (f16)0.0f;
    __syncthreads();

    float h = 0.0f;  // this lane's unit value (fp32)
    const f32x4 zf = {0.f, 0.f, 0.f, 0.f};

    auto step = [&](const f16* hsrc_raw, f16* hdst, int t) {
        const int j = t & 63;
        // uniform broadcast of x_t from the register window (v_readlane)
        const float xt = __builtin_bit_cast(
            float, __builtin_amdgcn_readlane(__builtin_bit_cast(int, xwin), j));
        const float gxr = fmaf(xt, wihr, br);
        const float gxz = fmaf(xt, wihz, bz);
        const float gxn = fmaf(xt, wihn, bin);

        const f16x8* hsrc = reinterpret_cast<const f16x8*>(hsrc_raw);
        const f16x8 A0 = hsrc[grp];       // h[8g..8g+7]      (ds_read_b128)
        const f16x8 A1 = hsrc[grp + 4];   // h[32+8g..32+8g+7]

        // 6 MFMAs: 3 gate chains of depth 2, interleaved (deps 3 slots apart)
        f32x4 c0r = __builtin_amdgcn_mfma_f32_16x16x32_f16(A0, Bf[0][0], zf, 0, 0, 0);
        f32x4 c0z = __builtin_amdgcn_mfma_f32_16x16x32_f16(A0, Bf[1][0], zf, 0, 0, 0);
        f32x4 c0n = __builtin_amdgcn_mfma_f32_16x16x32_f16(A0, Bf[2][0], zf, 0, 0, 0);
        f32x4 ccr = __builtin_amdgcn_mfma_f32_16x16x32_f16(A1, Bf[0][1], c0r, 0, 0, 0);
        f32x4 ccz = __builtin_amdgcn_mfma_f32_16x16x32_f16(A1, Bf[1][1], c0z, 0, 0, 0);
        f32x4 ccn = __builtin_amdgcn_mfma_f32_16x16x32_f16(A1, Bf[2][1], c0n, 0, 0, 0);

        // rows replicated -> reg 0 holds (W_gate . h)[u]; no select needed
        const float r = sigmoid_f(gxr + ccr[0]);
        const float z = sigmoid_f(gxz + ccz[0]);
        const float n = tanh_f(fmaf(r, ccn[0] + bhn, gxn));
        h = fmaf(z, h - n, n);  // (1-z)*n + z*h

        if (grp == 0) hdst[u] = (f16)h;   // 16 lanes/wave, disjoint units
        if (j == 63) {
            xwin = xnxt;                   // issued 64 steps ago -> ready
            const int idx = t + 65 + l;
            xnxt = (idx < T_LEN) ? x[xbase + idx] : 0.0f;
        }
        __syncthreads();  // hdst complete before any wave reads it next step
    };

    for (int t = 0; t < T_LEN; t += 2) {   // T_LEN even: clean 2x unroll
        step(hbuf[0], hbuf[1], t);
        step(hbuf[1], hbuf[0], t + 1);
    }

    // ---- epilogue: out[b] = h . W_fc + b_fc (fp32, exact register h) ----
    if (grp == 0) hf32[u] = h;
    __syncthreads();
    if (tid < HID) {
        float v = hf32[tid] * W_fc[tid];
#pragma unroll
        for (int off = 32; off > 0; off >>= 1) v += __shfl_down(v, off);
        if (tid == 0) out[b] = v + b_fc[0];
    }
}

extern "C" void kernel_launch(void* const* d_in, const int* in_sizes, int n_in,
                              void* d_out, int out_size, void* d_ws, size_t ws_size,
                              hipStream_t stream) {
    const float* x    = (const float*)d_in[0];
    const float* W_ih = (const float*)d_in[1];
    const float* W_hh = (const float*)d_in[2];
    const float* b_ih = (const float*)d_in[3];
    const float* b_hh = (const float*)d_in[4];
    const float* W_fc = (const float*)d_in[5];
    const float* b_fc = (const float*)d_in[6];
    float* out = (float*)d_out;

    const int B = 256;  // in_sizes[0] = B*T = 768000 -> B=256, T=3000
    gru_4wave<<<B, 256, 0, stream>>>(x, W_ih, W_hh, b_ih, b_hh, W_fc, b_fc, out);
}